// Round 12
// baseline (220.483 us; speedup 1.0000x reference)
//
#include <hip/hip_runtime.h>

typedef unsigned short u16;
typedef unsigned int   u32;
typedef __bf16 bf16;
typedef __attribute__((ext_vector_type(8))) __bf16 bf16x8;
typedef __attribute__((ext_vector_type(4))) float  f32x4;

// ---------------- helpers ----------------

__device__ __forceinline__ u16 f2bf(float f) {
  u32 u = __float_as_uint(f);
  u32 r = (u + 0x7fffu + ((u >> 16) & 1u)) >> 16;   // RNE
  return (u16)r;
}

// global -> LDS direct, 16B per lane. LDS dest is wave-uniform base + lane*16.
__device__ __forceinline__ void gload_lds16(const void* g, void* l) {
  __builtin_amdgcn_global_load_lds((__attribute__((address_space(1))) u32*)g,
                                   (__attribute__((address_space(3))) u32*)l,
                                   16, 0, 0);
}

__device__ __forceinline__ u32 cvt_pk_bf16(float lo, float hi) {
  u32 r;
  asm("v_cvt_pk_bf16_f32 %0, %1, %2" : "=v"(r) : "v"(lo), "v"(hi));
  return r;
}

#define SCL_LOG2E 0.1803368801111204f  /* (1/sqrt(64)) * log2(e) */

// ---------------- f32 -> bf16 converts ----------------

__global__ __launch_bounds__(256) void cvt_bf16_kernel(const float* __restrict__ in,
                                                       u16* __restrict__ out, int n4) {
  int i = blockIdx.x * blockDim.x + threadIdx.x;
  int stride = gridDim.x * blockDim.x;
  for (; i < n4; i += stride) {
    float4 v = ((const float4*)in)[i];
    uint2 o;
    o.x = (u32)f2bf(v.x) | ((u32)f2bf(v.y) << 16);
    o.y = (u32)f2bf(v.z) | ((u32)f2bf(v.w) << 16);
    ((uint2*)out)[i] = o;
  }
}

// all 4 weight matrices (1M elems each) in one launch: blocks 0-255 -> Wq, etc.
__global__ __launch_bounds__(256) void cvt4_kernel(const float* __restrict__ p0,
                                                   const float* __restrict__ p1,
                                                   const float* __restrict__ p2,
                                                   const float* __restrict__ p3,
                                                   u16* o0, u16* o1, u16* o2, u16* o3) {
  const int which = blockIdx.x >> 8;
  const float* in = which == 0 ? p0 : which == 1 ? p1 : which == 2 ? p2 : p3;
  u16* out = which == 0 ? o0 : which == 1 ? o1 : which == 2 ? o2 : o3;
  int i = (blockIdx.x & 255) * 256 + threadIdx.x;
  #pragma unroll
  for (int r = 0; r < 4; ++r, i += 65536) {
    float4 v = ((const float4*)in)[i];
    uint2 o;
    o.x = (u32)f2bf(v.x) | ((u32)f2bf(v.y) << 16);
    o.y = (u32)f2bf(v.z) | ((u32)f2bf(v.w) << 16);
    ((uint2*)out)[i] = o;
  }
}

// ---------------- GEMM core: quad-buffered deep pipeline ----------------
// C[m,n] = sum_k A[m,k]*W[n,k] + bias[n]; M=8192, N=1024 (per W), K=1024.
// 128x128 tile, BK=32, 4 waves (2x2), 16x16x32 MFMA, XOR-swizzled staging.
// FOUR LDS slots (64KB), prefetch distance 3, ONE raw s_barrier per K-step,
// counted vmcnt(8) -- staging loads are never drained to 0 in steady state
// (each load gets ~2.5 K-steps of latency cover vs ~1 with 2-slot+syncthreads).
// Ledger (4 loads/thread/tile, FIFO): prologue stages tiles 0,1,2 (12 out).
//   iter t: vmcnt(8) [tile t landed] ; s_barrier ; stage(t+3 -> slot[(t+3)&3]
//   == slot[(t-1)&3], whose readers all passed this barrier) ; compute(t).
//   Tail: t=29 vmcnt(8), t=30 vmcnt(4), t=31 vmcnt(0).  Unrolled x4 so slot
//   indices are static (address hoisting).

#define GK 1024
#define GN 1024

#define GEMM_PRELUDE                                                            \
  const int tid  = threadIdx.x;                                                 \
  const int lane = tid & 63;                                                    \
  const int w    = tid >> 6;                                                    \
  const int wm   = w >> 1, wn = w & 1;                                          \
  const int rgrp = lane >> 4, rlo = lane & 15;                                  \
  const int c0 = (w * 2 + 0) * 64 + lane;                                       \
  const int c1 = (w * 2 + 1) * 64 + lane;                                       \
  const int r0 = c0 >> 2, col0 = (((c0 & 3) ^ (r0 & 3)) * 8);                   \
  const int r1 = c1 >> 2, col1 = (((c1 & 3) ^ (r1 & 3)) * 8);                   \
  const u16* aS0 = A + (size_t)(m0 + r0) * GK + col0;                           \
  const u16* aS1 = A + (size_t)(m0 + r1) * GK + col1;                           \
  const u16* bS0 = W + (size_t)(n0 + r0) * GK + col0;                           \
  const u16* bS1 = W + (size_t)(n0 + r1) * GK + col1;                           \
  auto stage = [&](u16* dA, u16* dB) {                                          \
    gload_lds16(aS0, dA + (w * 2 + 0) * 512);                                   \
    gload_lds16(aS1, dA + (w * 2 + 1) * 512);                                   \
    gload_lds16(bS0, dB + (w * 2 + 0) * 512);                                   \
    gload_lds16(bS1, dB + (w * 2 + 1) * 512);                                   \
    aS0 += 32; aS1 += 32; bS0 += 32; bS1 += 32;                                 \
  };                                                                            \
  f32x4 acc[4][4] = {};                                                         \
  auto compute = [&](const u16* sAc, const u16* sBc) {                          \
    bf16x8 a[4], b[4];                                                          \
    _Pragma("unroll")                                                           \
    for (int i = 0; i < 4; ++i) {                                               \
      int row = wm * 64 + i * 16 + rlo;                                         \
      int cb  = rgrp ^ (row & 3);                                               \
      a[i] = *(const bf16x8*)&sAc[row * 32 + cb * 8];                           \
    }                                                                           \
    _Pragma("unroll")                                                           \
    for (int j = 0; j < 4; ++j) {                                               \
      int row = wn * 64 + j * 16 + rlo;                                         \
      int cb  = rgrp ^ (row & 3);                                               \
      b[j] = *(const bf16x8*)&sBc[row * 32 + cb * 8];                           \
    }                                                                           \
    _Pragma("unroll")                                                           \
    for (int i = 0; i < 4; ++i)                                                 \
      _Pragma("unroll")                                                         \
      for (int j = 0; j < 4; ++j)                                               \
        acc[i][j] = __builtin_amdgcn_mfma_f32_16x16x32_bf16(a[i], b[j],         \
                                                            acc[i][j], 0, 0, 0);\
  };                                                                            \
  /* prologue: stage tiles 0,1,2 (12 loads outstanding) */                      \
  stage(sA[0], sB[0]); stage(sA[1], sB[1]); stage(sA[2], sB[2]);                \
  /* steady: t = 0..27 (stage t+3), slots static via x4 unroll */               \
  for (int t = 0; t < 28; t += 4) {                                             \
    asm volatile("s_waitcnt vmcnt(8)" ::: "memory");                            \
    __builtin_amdgcn_s_barrier(); __builtin_amdgcn_sched_barrier(0);            \
    stage(sA[3], sB[3]); compute(sA[0], sB[0]);                                 \
    asm volatile("s_waitcnt vmcnt(8)" ::: "memory");                            \
    __builtin_amdgcn_s_barrier(); __builtin_amdgcn_sched_barrier(0);            \
    stage(sA[0], sB[0]); compute(sA[1], sB[1]);                                 \
    asm volatile("s_waitcnt vmcnt(8)" ::: "memory");                            \
    __builtin_amdgcn_s_barrier(); __builtin_amdgcn_sched_barrier(0);            \
    stage(sA[1], sB[1]); compute(sA[2], sB[2]);                                 \
    asm volatile("s_waitcnt vmcnt(8)" ::: "memory");                            \
    __builtin_amdgcn_s_barrier(); __builtin_amdgcn_sched_barrier(0);            \
    stage(sA[2], sB[2]); compute(sA[3], sB[3]);                                 \
  }                                                                             \
  /* t=28: stage tile 31 -> slot 3 */                                           \
  asm volatile("s_waitcnt vmcnt(8)" ::: "memory");                              \
  __builtin_amdgcn_s_barrier(); __builtin_amdgcn_sched_barrier(0);              \
  stage(sA[3], sB[3]); compute(sA[0], sB[0]);                                   \
  /* t=29..31: no stages */                                                     \
  asm volatile("s_waitcnt vmcnt(8)" ::: "memory");                              \
  __builtin_amdgcn_s_barrier(); __builtin_amdgcn_sched_barrier(0);              \
  compute(sA[1], sB[1]);                                                        \
  asm volatile("s_waitcnt vmcnt(4)" ::: "memory");                              \
  __builtin_amdgcn_s_barrier(); __builtin_amdgcn_sched_barrier(0);              \
  compute(sA[2], sB[2]);                                                        \
  asm volatile("s_waitcnt vmcnt(0)" ::: "memory");                              \
  __builtin_amdgcn_s_barrier(); __builtin_amdgcn_sched_barrier(0);              \
  compute(sA[3], sB[3]);

// fused QKV projection: grid 1536 = 3 x 512.
//   Q -> plain [8192][1024] bf16 rows
//   K -> plain [8192][1024] bf16 rows, PRE-SCALED by SCL_LOG2E
//   V -> [BH][64][T] transposed, 8B-packed stores
__global__ __launch_bounds__(256) void gemm_qkv_kernel(const u16* __restrict__ A,
                                                       const u16* __restrict__ Wq,
                                                       const u16* __restrict__ Wk,
                                                       const u16* __restrict__ Wv,
                                                       const float* __restrict__ bq,
                                                       const float* __restrict__ bk,
                                                       const float* __restrict__ bv,
                                                       u16* __restrict__ Qo,
                                                       u16* __restrict__ Ko,
                                                       u16* __restrict__ Vo) {
  __shared__ u16 sA[4][128 * 32];
  __shared__ u16 sB[4][128 * 32];

  const int lid  = (blockIdx.x & 7) * 192 + (blockIdx.x >> 3);
  const int which = lid >> 9;            // 0..2
  const int sub   = lid & 511;
  const u16*  W    = which == 0 ? Wq : which == 1 ? Wk : Wv;
  const float* bias = which == 0 ? bq : which == 1 ? bk : bv;
  const int tn   = sub & 7;
  const int tm   = sub >> 3;
  const int m0   = tm * 128, n0 = tn * 128;

  GEMM_PRELUDE

  if (which <= 1) {
    u16* out = which == 0 ? Qo : Ko;
    const float scl = which == 0 ? 1.0f : SCL_LOG2E;
    #pragma unroll
    for (int i = 0; i < 4; ++i)
      #pragma unroll
      for (int j = 0; j < 4; ++j)
        #pragma unroll
        for (int r = 0; r < 4; ++r) {
          int m = m0 + wm * 64 + i * 16 + rgrp * 4 + r;
          int n = n0 + wn * 64 + j * 16 + rlo;
          float v = (acc[i][j][r] + bias[n]) * scl;
          out[(size_t)m * GN + n] = (u16)__builtin_bit_cast(u16, (bf16)v);
        }
  } else {
    #pragma unroll
    for (int i = 0; i < 4; ++i)
      #pragma unroll
      for (int j = 0; j < 4; ++j) {
        int mb = m0 + wm * 64 + i * 16 + rgrp * 4;
        int n  = n0 + wn * 64 + j * 16 + rlo;
        int b = mb >> 11, t = mb & 2047, h = n >> 6, hd = n & 63;
        float bv_ = bias[n];
        uint2 st;
        st.x = cvt_pk_bf16(acc[i][j][0] + bv_, acc[i][j][1] + bv_);
        st.y = cvt_pk_bf16(acc[i][j][2] + bv_, acc[i][j][3] + bv_);
        *(uint2*)&Vo[((size_t)(b * 16 + h) * 64 + hd) * 2048 + t] = st;
      }
  }
}

__global__ __launch_bounds__(256) void gemm_out_kernel(const u16* __restrict__ A,
                                                       const u16* __restrict__ W,
                                                       const float* __restrict__ bias,
                                                       float* __restrict__ Cout) {
  __shared__ u16 sA[4][128 * 32];
  __shared__ u16 sB[4][128 * 32];

  const int lid  = (blockIdx.x & 7) * 64 + (blockIdx.x >> 3);
  const int tn   = lid & 7;
  const int tm   = lid >> 3;
  const int m0   = tm * 128, n0 = tn * 128;

  GEMM_PRELUDE

  #pragma unroll
  for (int i = 0; i < 4; ++i)
    #pragma unroll
    for (int j = 0; j < 4; ++j)
      #pragma unroll
      for (int r = 0; r < 4; ++r) {
        int m = m0 + wm * 64 + i * 16 + rgrp * 4 + r;
        int n = n0 + wn * 64 + j * 16 + rlo;
        Cout[(size_t)m * GN + n] = acc[i][j][r] + bias[n];
      }
}

// ---------------- fused flash attention (KVBLK=64, counted-vmcnt pipeline) ----
// Unchanged from Round 11 (best measured: 101 us).

__global__ __launch_bounds__(256) void attn_kernel(const u16* __restrict__ Q,
                                                   const u16* __restrict__ K,
                                                   const u16* __restrict__ Vt,
                                                   bf16* __restrict__ O) {
  __shared__ u16 sK[2][64 * 64];
  __shared__ u16 sV[2][64 * 64];

  const int tid  = threadIdx.x;
  const int lane = tid & 63;
  const int w    = tid >> 6;
  const int rgrp = lane >> 4, rlo = lane & 15;
  const int bid  = (blockIdx.x & 7) * 128 + (blockIdx.x >> 3);
  const int qt   = bid & 15;
  const int bh   = bid >> 4;
  const int b    = bh >> 4, h = bh & 15;

  const u16* Qh = Q  + (size_t)b * 2048 * 1024 + h * 64;   // row stride 1024
  const u16* Kh = K  + (size_t)b * 2048 * 1024 + h * 64;   // row stride 1024
  const u16* Vh = Vt + (size_t)bh * 64 * 2048;             // row stride 2048

  const int c0 = (w * 2 + 0) * 64 + lane;
  const int c1 = (w * 2 + 1) * 64 + lane;
  const int r0 = c0 >> 3, col0 = ((c0 & 7) ^ (r0 & 7)) * 8;
  const int r1 = c1 >> 3, col1 = ((c1 & 7) ^ (r1 & 7)) * 8;
  const u16* kb0 = Kh + (size_t)r0 * 1024 + col0;
  const u16* kb1 = Kh + (size_t)r1 * 1024 + col1;
  const u16* vb0 = Vh + (size_t)r0 * 2048 + col0;
  const u16* vb1 = Vh + (size_t)r1 * 2048 + col1;

  // K loads first, then V (vmcnt ledger depends on this order)
  auto stage = [&](u16* dK, u16* dV) {
    gload_lds16(kb0, dK + (w * 2 + 0) * 512);
    gload_lds16(kb1, dK + (w * 2 + 1) * 512);
    gload_lds16(vb0, dV + (w * 2 + 0) * 512);
    gload_lds16(vb1, dV + (w * 2 + 1) * 512);
    kb0 += 65536; kb1 += 65536;   // 64 kv rows * 1024
    vb0 += 64;    vb1 += 64;      // 64 kv cols
  };

  stage(sK[0], sV[0]);

  bf16x8 bQ[2][2];
  #pragma unroll
  for (int qg = 0; qg < 2; ++qg) {
    int q0 = qt * 128 + w * 32 + qg * 16 + rlo;
    bQ[qg][0] = *(const bf16x8*)&Qh[(size_t)q0 * 1024 + rgrp * 8];
    bQ[qg][1] = *(const bf16x8*)&Qh[(size_t)q0 * 1024 + 32 + rgrp * 8];
  }

  bf16x8 vones;
  #pragma unroll
  for (int i = 0; i < 8; ++i) vones[i] = (bf16)1.0f;
  const f32x4 FZ = {0.f, 0.f, 0.f, 0.f};

  asm volatile("s_waitcnt vmcnt(0)" ::: "memory");
  __builtin_amdgcn_s_barrier();
  __builtin_amdgcn_sched_barrier(0);

  f32x4 lden[2] = {};
  f32x4 o[2][4] = {};
  f32x4 sT[2][4];

  auto qk = [&](const u16* sKc) {
    __builtin_amdgcn_s_setprio(1);
    #pragma unroll
    for (int nt = 0; nt < 4; ++nt) {
      int row = nt * 16 + rlo;
      int cb0_ = (0 + rgrp) ^ (row & 7);
      int cb1_ = (4 + rgrp) ^ (row & 7);
      bf16x8 aK0 = *(const bf16x8*)&sKc[row * 64 + cb0_ * 8];
      bf16x8 aK1 = *(const bf16x8*)&sKc[row * 64 + cb1_ * 8];
      sT[0][nt] = __builtin_amdgcn_mfma_f32_16x16x32_bf16(aK0, bQ[0][0], FZ, 0, 0, 0);
      sT[1][nt] = __builtin_amdgcn_mfma_f32_16x16x32_bf16(aK0, bQ[1][0], FZ, 0, 0, 0);
      sT[0][nt] = __builtin_amdgcn_mfma_f32_16x16x32_bf16(aK1, bQ[0][1], sT[0][nt], 0, 0, 0);
      sT[1][nt] = __builtin_amdgcn_mfma_f32_16x16x32_bf16(aK1, bQ[1][1], sT[1][nt], 0, 0, 0);
    }
    __builtin_amdgcn_s_setprio(0);
  };

  auto smpv = [&](const u16* sVc) {
    #pragma unroll
    for (int qg = 0; qg < 2; ++qg) {
      #pragma unroll
      for (int nt = 0; nt < 4; ++nt)
        #pragma unroll
        for (int r = 0; r < 4; ++r)
          sT[qg][nt][r] = __builtin_amdgcn_exp2f(sT[qg][nt][r]);

      u32 pw[4][2];
      #pragma unroll
      for (int nt = 0; nt < 4; ++nt) {
        pw[nt][0] = cvt_pk_bf16(sT[qg][nt][0], sT[qg][nt][1]);
        pw[nt][1] = cvt_pk_bf16(sT[qg][nt][2], sT[qg][nt][3]);
      }
      bf16x8 bP[2];
      #pragma unroll
      for (int kk = 0; kk < 2; ++kk) {
        u32 a0 = pw[2 * kk][0], b0 = pw[2 * kk + 1][0];
        u32 a1 = pw[2 * kk][1], b1 = pw[2 * kk + 1][1];
        asm("v_permlane32_swap_b32 %0, %1" : "+v"(a0), "+v"(b0));
        asm("v_permlane16_swap_b32 %0, %1" : "+v"(a0), "+v"(b0));
        asm("v_permlane32_swap_b32 %0, %1" : "+v"(a1), "+v"(b1));
        asm("v_permlane16_swap_b32 %0, %1" : "+v"(a1), "+v"(b1));
        union { u32 u[4]; bf16x8 v; } fu;
        fu.u[0] = a0; fu.u[1] = a1; fu.u[2] = b0; fu.u[3] = b1;
        bP[kk] = fu.v;
      }

      __builtin_amdgcn_s_setprio(1);
      #pragma unroll
      for (int kk = 0; kk < 2; ++kk) {
        lden[qg] = __builtin_amdgcn_mfma_f32_16x16x32_bf16(vones, bP[kk], lden[qg], 0, 0, 0);
        #pragma unroll
        for (int dt = 0; dt < 4; ++dt) {
          int rowv = dt * 16 + rlo;
          int cbv  = (kk * 4 + rgrp) ^ (rowv & 7);
          bf16x8 aV = *(const bf16x8*)&sVc[rowv * 64 + cbv * 8];
          o[qg][dt] = __builtin_amdgcn_mfma_f32_16x16x32_bf16(aV, bP[kk], o[qg][dt], 0, 0, 0);
        }
      }
      __builtin_amdgcn_s_setprio(0);
    }
  };

  auto iter = [&](const u16* sKc, const u16* sVc, u16* sKn, u16* sVn) {
    stage(sKn, sVn);                                  // K(t+1) x2, V(t+1) x2
    qk(sKc);
    asm volatile("s_waitcnt vmcnt(4)" ::: "memory");  // V(t) landed
    __builtin_amdgcn_s_barrier();
    __builtin_amdgcn_sched_barrier(0);
    smpv(sVc);
    asm volatile("s_waitcnt vmcnt(2)" ::: "memory");  // K(t+1) landed
    __builtin_amdgcn_s_barrier();
    __builtin_amdgcn_sched_barrier(0);
  };

  for (int it = 0; it < 15; ++it) {
    iter(sK[0], sV[0], sK[1], sV[1]);
    iter(sK[1], sV[1], sK[0], sV[0]);
  }
  iter(sK[0], sV[0], sK[1], sV[1]);                   // t=30, stages tile 31

  qk(sK[1]);
  asm volatile("s_waitcnt vmcnt(0)" ::: "memory");
  __builtin_amdgcn_s_barrier();
  __builtin_amdgcn_sched_barrier(0);
  smpv(sV[1]);

  #pragma unroll
  for (int qg = 0; qg < 2; ++qg) {
    const float inv = 1.0f / lden[qg][0];
    const int tq = qt * 128 + w * 32 + qg * 16 + rlo;
    #pragma unroll
    for (int dt = 0; dt < 4; ++dt) {
      uint2 st;
      st.x = cvt_pk_bf16(o[qg][dt][0] * inv, o[qg][dt][1] * inv);
      st.y = cvt_pk_bf16(o[qg][dt][2] * inv, o[qg][dt][3] * inv);
      *(uint2*)&O[((size_t)(b * 2048 + tq)) * 1024 + h * 64 + dt * 16 + rgrp * 4] = st;
    }
  }
}

// ---------------- launch ----------------

extern "C" void kernel_launch(void* const* d_in, const int* in_sizes, int n_in,
                              void* d_out, int out_size, void* d_ws, size_t ws_size,
                              hipStream_t stream) {
  const float* x  = (const float*)d_in[0];
  const float* Wq = (const float*)d_in[1];
  const float* bq = (const float*)d_in[2];
  const float* Wk = (const float*)d_in[3];
  const float* bk = (const float*)d_in[4];
  const float* Wv = (const float*)d_in[5];
  const float* bv = (const float*)d_in[6];
  const float* Wo = (const float*)d_in[7];
  const float* bo = (const float*)d_in[8];

  char* ws = (char*)d_ws;
  u16* xb  = (u16*)(ws);                      // 16 MiB  [8192][1024]
  u16* Wqb = (u16*)(ws + 16777216);           //  2 MiB
  u16* Wkb = (u16*)(ws + 18874368);
  u16* Wvb = (u16*)(ws + 20971520);
  u16* Wob = (u16*)(ws + 23068672);
  u16* Qb  = (u16*)(ws + 25165824);           // 16 MiB  [8192][1024]
  u16* Kb  = (u16*)(ws + 41943040);           // 16 MiB  [8192][1024] (pre-scaled)
  u16* Vtb = (u16*)(ws + 58720256);           // 16 MiB  [BH][64][T]
  u16* Ab  = (u16*)(ws + 75497472);           // 16 MiB  [B][T][1024]

  cvt_bf16_kernel<<<4096, 256, 0, stream>>>(x, xb, 8388608 / 4);
  cvt4_kernel<<<1024, 256, 0, stream>>>(Wq, Wk, Wv, Wo, Wqb, Wkb, Wvb, Wob);

  gemm_qkv_kernel<<<1536, 256, 0, stream>>>(xb, Wqb, Wkb, Wvb, bq, bk, bv, Qb, Kb, Vtb);

  attn_kernel<<<1024, 256, 0, stream>>>(Qb, Kb, Vtb, (bf16*)Ab);

  gemm_out_kernel<<<512, 256, 0, stream>>>(Ab, Wob, bo, (float*)d_out);
}

// Round 13
// 211.866 us; speedup vs baseline: 1.0407x; 1.0407x over previous
//
#include <hip/hip_runtime.h>

typedef unsigned short u16;
typedef unsigned int   u32;
typedef __bf16 bf16;
typedef __attribute__((ext_vector_type(8))) __bf16 bf16x8;
typedef __attribute__((ext_vector_type(4))) float  f32x4;

// ---------------- helpers ----------------

__device__ __forceinline__ u16 f2bf(float f) {
  u32 u = __float_as_uint(f);
  u32 r = (u + 0x7fffu + ((u >> 16) & 1u)) >> 16;   // RNE
  return (u16)r;
}

// global -> LDS direct, 16B per lane. LDS dest is wave-uniform base + lane*16.
__device__ __forceinline__ void gload_lds16(const void* g, void* l) {
  __builtin_amdgcn_global_load_lds((__attribute__((address_space(1))) u32*)g,
                                   (__attribute__((address_space(3))) u32*)l,
                                   16, 0, 0);
}

__device__ __forceinline__ u32 cvt_pk_bf16(float lo, float hi) {
  u32 r;
  asm("v_cvt_pk_bf16_f32 %0, %1, %2" : "=v"(r) : "v"(lo), "v"(hi));
  return r;
}

#define SCL_LOG2E 0.1803368801111204f  /* (1/sqrt(64)) * log2(e) */

// ---------------- fused f32 -> bf16 convert (x + all 4 weights, one launch) ---
// blocks 0..4095: x (8M elems); blocks 4096..5119: Wq/Wk/Wv/Wo (1M each).

__global__ __launch_bounds__(256) void cvt_all_kernel(const float* __restrict__ x,
                                                      const float* __restrict__ p0,
                                                      const float* __restrict__ p1,
                                                      const float* __restrict__ p2,
                                                      const float* __restrict__ p3,
                                                      u16* __restrict__ xo,
                                                      u16* o0, u16* o1, u16* o2, u16* o3) {
  const int bid = blockIdx.x;
  if (bid < 4096) {
    int i = bid * 256 + threadIdx.x;            // 1M threads, 2M float4s
    #pragma unroll
    for (int r = 0; r < 2; ++r, i += 1048576) {
      float4 v = ((const float4*)x)[i];
      uint2 o;
      o.x = (u32)f2bf(v.x) | ((u32)f2bf(v.y) << 16);
      o.y = (u32)f2bf(v.z) | ((u32)f2bf(v.w) << 16);
      ((uint2*)xo)[i] = o;
    }
  } else {
    const int wb = bid - 4096;
    const int which = wb >> 8;
    const float* in = which == 0 ? p0 : which == 1 ? p1 : which == 2 ? p2 : p3;
    u16* out = which == 0 ? o0 : which == 1 ? o1 : which == 2 ? o2 : o3;
    int i = (wb & 255) * 256 + threadIdx.x;
    #pragma unroll
    for (int r = 0; r < 4; ++r, i += 65536) {
      float4 v = ((const float4*)in)[i];
      uint2 o;
      o.x = (u32)f2bf(v.x) | ((u32)f2bf(v.y) << 16);
      o.y = (u32)f2bf(v.z) | ((u32)f2bf(v.w) << 16);
      ((uint2*)out)[i] = o;
    }
  }
}

// ---------------- GEMM core (2-slot dbuf + syncthreads — best measured) ------
// C[m,n] = sum_k A[m,k]*W[n,k] + bias[n]; M=8192, N=1024 (per W), K=1024.
// 128x128 tile, BK=32, 4 waves (2x2), 16x16x32 MFMA, XOR-swizzled staging
// (both-sides involution), static buffer selection (addresses hoist).

#define GK 1024
#define GN 1024

__global__ __launch_bounds__(256) void gemm_qkv_kernel(const u16* __restrict__ A,
                                                       const u16* __restrict__ Wq,
                                                       const u16* __restrict__ Wk,
                                                       const u16* __restrict__ Wv,
                                                       const float* __restrict__ bq,
                                                       const float* __restrict__ bk,
                                                       const float* __restrict__ bv,
                                                       u16* __restrict__ Qo,
                                                       u16* __restrict__ Ko,
                                                       u16* __restrict__ Vo) {
  __shared__ u16 sA[2][128 * 32];
  __shared__ u16 sB[2][128 * 32];

  const int tid  = threadIdx.x;
  const int lane = tid & 63;
  const int w    = tid >> 6;
  const int wm   = w >> 1, wn = w & 1;
  const int lid  = (blockIdx.x & 7) * 192 + (blockIdx.x >> 3);
  const int which = lid >> 9;            // 0..2
  const int sub   = lid & 511;
  const u16*  W    = which == 0 ? Wq : which == 1 ? Wk : Wv;
  const float* bias = which == 0 ? bq : which == 1 ? bk : bv;
  const int tn   = sub & 7;
  const int tm   = sub >> 3;
  const int m0   = tm * 128, n0 = tn * 128;
  const int rgrp = lane >> 4, rlo = lane & 15;

  const int c0 = (w * 2 + 0) * 64 + lane;
  const int c1 = (w * 2 + 1) * 64 + lane;
  const int r0 = c0 >> 2, col0 = (((c0 & 3) ^ (r0 & 3)) * 8);
  const int r1 = c1 >> 2, col1 = (((c1 & 3) ^ (r1 & 3)) * 8);
  const u16* aS0 = A + (size_t)(m0 + r0) * GK + col0;
  const u16* aS1 = A + (size_t)(m0 + r1) * GK + col1;
  const u16* bS0 = W + (size_t)(n0 + r0) * GK + col0;
  const u16* bS1 = W + (size_t)(n0 + r1) * GK + col1;

  auto stage = [&](u16* dA, u16* dB, int kt) {
    int k0 = kt * 32;
    gload_lds16(aS0 + k0, dA + (w * 2 + 0) * 512);
    gload_lds16(aS1 + k0, dA + (w * 2 + 1) * 512);
    gload_lds16(bS0 + k0, dB + (w * 2 + 0) * 512);
    gload_lds16(bS1 + k0, dB + (w * 2 + 1) * 512);
  };

  f32x4 acc[4][4] = {};

  auto compute = [&](const u16* sAc, const u16* sBc) {
    bf16x8 a[4], b[4];
    #pragma unroll
    for (int i = 0; i < 4; ++i) {
      int row = wm * 64 + i * 16 + rlo;
      int cb  = rgrp ^ (row & 3);
      a[i] = *(const bf16x8*)&sAc[row * 32 + cb * 8];
    }
    #pragma unroll
    for (int j = 0; j < 4; ++j) {
      int row = wn * 64 + j * 16 + rlo;
      int cb  = rgrp ^ (row & 3);
      b[j] = *(const bf16x8*)&sBc[row * 32 + cb * 8];
    }
    #pragma unroll
    for (int i = 0; i < 4; ++i)
      #pragma unroll
      for (int j = 0; j < 4; ++j)
        acc[i][j] = __builtin_amdgcn_mfma_f32_16x16x32_bf16(a[i], b[j], acc[i][j], 0, 0, 0);
  };

  stage(sA[0], sB[0], 0);
  __syncthreads();

  for (int kt = 0; kt < GK / 32; kt += 2) {
    stage(sA[1], sB[1], kt + 1);
    compute(sA[0], sB[0]);
    __syncthreads();
    if (kt + 2 < GK / 32) stage(sA[0], sB[0], kt + 2);
    compute(sA[1], sB[1]);
    __syncthreads();
  }

  if (which <= 1) {
    u16* out = which == 0 ? Qo : Ko;
    const float scl = which == 0 ? 1.0f : SCL_LOG2E;
    #pragma unroll
    for (int i = 0; i < 4; ++i)
      #pragma unroll
      for (int j = 0; j < 4; ++j)
        #pragma unroll
        for (int r = 0; r < 4; ++r) {
          int m = m0 + wm * 64 + i * 16 + rgrp * 4 + r;
          int n = n0 + wn * 64 + j * 16 + rlo;
          float v = (acc[i][j][r] + bias[n]) * scl;
          out[(size_t)m * GN + n] = (u16)__builtin_bit_cast(u16, (bf16)v);
        }
  } else {
    #pragma unroll
    for (int i = 0; i < 4; ++i)
      #pragma unroll
      for (int j = 0; j < 4; ++j) {
        int mb = m0 + wm * 64 + i * 16 + rgrp * 4;
        int n  = n0 + wn * 64 + j * 16 + rlo;
        int b = mb >> 11, t = mb & 2047, h = n >> 6, hd = n & 63;
        float bv_ = bias[n];
        uint2 st;
        st.x = cvt_pk_bf16(acc[i][j][0] + bv_, acc[i][j][1] + bv_);
        st.y = cvt_pk_bf16(acc[i][j][2] + bv_, acc[i][j][3] + bv_);
        *(uint2*)&Vo[((size_t)(b * 16 + h) * 64 + hd) * 2048 + t] = st;
      }
  }
}

__global__ __launch_bounds__(256) void gemm_out_kernel(const u16* __restrict__ A,
                                                       const u16* __restrict__ W,
                                                       const float* __restrict__ bias,
                                                       float* __restrict__ Cout) {
  __shared__ u16 sA[2][128 * 32];
  __shared__ u16 sB[2][128 * 32];

  const int tid  = threadIdx.x;
  const int lane = tid & 63;
  const int w    = tid >> 6;
  const int wm   = w >> 1, wn = w & 1;
  const int lid  = (blockIdx.x & 7) * 64 + (blockIdx.x >> 3);
  const int tn   = lid & 7;
  const int tm   = lid >> 3;
  const int m0   = tm * 128, n0 = tn * 128;
  const int rgrp = lane >> 4, rlo = lane & 15;

  const int c0 = (w * 2 + 0) * 64 + lane;
  const int c1 = (w * 2 + 1) * 64 + lane;
  const int r0 = c0 >> 2, col0 = (((c0 & 3) ^ (r0 & 3)) * 8);
  const int r1 = c1 >> 2, col1 = (((c1 & 3) ^ (r1 & 3)) * 8);
  const u16* aS0 = A + (size_t)(m0 + r0) * GK + col0;
  const u16* aS1 = A + (size_t)(m0 + r1) * GK + col1;
  const u16* bS0 = W + (size_t)(n0 + r0) * GK + col0;
  const u16* bS1 = W + (size_t)(n0 + r1) * GK + col1;

  auto stage = [&](u16* dA, u16* dB, int kt) {
    int k0 = kt * 32;
    gload_lds16(aS0 + k0, dA + (w * 2 + 0) * 512);
    gload_lds16(aS1 + k0, dA + (w * 2 + 1) * 512);
    gload_lds16(bS0 + k0, dB + (w * 2 + 0) * 512);
    gload_lds16(bS1 + k0, dB + (w * 2 + 1) * 512);
  };

  f32x4 acc[4][4] = {};

  auto compute = [&](const u16* sAc, const u16* sBc) {
    bf16x8 a[4], b[4];
    #pragma unroll
    for (int i = 0; i < 4; ++i) {
      int row = wm * 64 + i * 16 + rlo;
      int cb  = rgrp ^ (row & 3);
      a[i] = *(const bf16x8*)&sAc[row * 32 + cb * 8];
    }
    #pragma unroll
    for (int j = 0; j < 4; ++j) {
      int row = wn * 64 + j * 16 + rlo;
      int cb  = rgrp ^ (row & 3);
      b[j] = *(const bf16x8*)&sBc[row * 32 + cb * 8];
    }
    #pragma unroll
    for (int i = 0; i < 4; ++i)
      #pragma unroll
      for (int j = 0; j < 4; ++j)
        acc[i][j] = __builtin_amdgcn_mfma_f32_16x16x32_bf16(a[i], b[j], acc[i][j], 0, 0, 0);
  };

  stage(sA[0], sB[0], 0);
  __syncthreads();

  for (int kt = 0; kt < GK / 32; kt += 2) {
    stage(sA[1], sB[1], kt + 1);
    compute(sA[0], sB[0]);
    __syncthreads();
    if (kt + 2 < GK / 32) stage(sA[0], sB[0], kt + 2);
    compute(sA[1], sB[1]);
    __syncthreads();
  }

  #pragma unroll
  for (int i = 0; i < 4; ++i)
    #pragma unroll
    for (int j = 0; j < 4; ++j)
      #pragma unroll
      for (int r = 0; r < 4; ++r) {
        int m = m0 + wm * 64 + i * 16 + rgrp * 4 + r;
        int n = n0 + wn * 64 + j * 16 + rlo;
        Cout[(size_t)m * GN + n] = acc[i][j][r] + bias[n];
      }
}

// ---------------- fused flash attention (KVBLK=64, counted-vmcnt pipeline) ----
// Unchanged from Round 11 (best measured: 101.3 us).

__global__ __launch_bounds__(256) void attn_kernel(const u16* __restrict__ Q,
                                                   const u16* __restrict__ K,
                                                   const u16* __restrict__ Vt,
                                                   bf16* __restrict__ O) {
  __shared__ u16 sK[2][64 * 64];
  __shared__ u16 sV[2][64 * 64];

  const int tid  = threadIdx.x;
  const int lane = tid & 63;
  const int w    = tid >> 6;
  const int rgrp = lane >> 4, rlo = lane & 15;
  const int bid  = (blockIdx.x & 7) * 128 + (blockIdx.x >> 3);
  const int qt   = bid & 15;
  const int bh   = bid >> 4;
  const int b    = bh >> 4, h = bh & 15;

  const u16* Qh = Q  + (size_t)b * 2048 * 1024 + h * 64;   // row stride 1024
  const u16* Kh = K  + (size_t)b * 2048 * 1024 + h * 64;   // row stride 1024
  const u16* Vh = Vt + (size_t)bh * 64 * 2048;             // row stride 2048

  const int c0 = (w * 2 + 0) * 64 + lane;
  const int c1 = (w * 2 + 1) * 64 + lane;
  const int r0 = c0 >> 3, col0 = ((c0 & 7) ^ (r0 & 7)) * 8;
  const int r1 = c1 >> 3, col1 = ((c1 & 7) ^ (r1 & 7)) * 8;
  const u16* kb0 = Kh + (size_t)r0 * 1024 + col0;
  const u16* kb1 = Kh + (size_t)r1 * 1024 + col1;
  const u16* vb0 = Vh + (size_t)r0 * 2048 + col0;
  const u16* vb1 = Vh + (size_t)r1 * 2048 + col1;

  // K loads first, then V (vmcnt ledger depends on this order)
  auto stage = [&](u16* dK, u16* dV) {
    gload_lds16(kb0, dK + (w * 2 + 0) * 512);
    gload_lds16(kb1, dK + (w * 2 + 1) * 512);
    gload_lds16(vb0, dV + (w * 2 + 0) * 512);
    gload_lds16(vb1, dV + (w * 2 + 1) * 512);
    kb0 += 65536; kb1 += 65536;   // 64 kv rows * 1024
    vb0 += 64;    vb1 += 64;      // 64 kv cols
  };

  stage(sK[0], sV[0]);

  bf16x8 bQ[2][2];
  #pragma unroll
  for (int qg = 0; qg < 2; ++qg) {
    int q0 = qt * 128 + w * 32 + qg * 16 + rlo;
    bQ[qg][0] = *(const bf16x8*)&Qh[(size_t)q0 * 1024 + rgrp * 8];
    bQ[qg][1] = *(const bf16x8*)&Qh[(size_t)q0 * 1024 + 32 + rgrp * 8];
  }

  bf16x8 vones;
  #pragma unroll
  for (int i = 0; i < 8; ++i) vones[i] = (bf16)1.0f;
  const f32x4 FZ = {0.f, 0.f, 0.f, 0.f};

  asm volatile("s_waitcnt vmcnt(0)" ::: "memory");
  __builtin_amdgcn_s_barrier();
  __builtin_amdgcn_sched_barrier(0);

  f32x4 lden[2] = {};
  f32x4 o[2][4] = {};
  f32x4 sT[2][4];

  auto qk = [&](const u16* sKc) {
    __builtin_amdgcn_s_setprio(1);
    #pragma unroll
    for (int nt = 0; nt < 4; ++nt) {
      int row = nt * 16 + rlo;
      int cb0_ = (0 + rgrp) ^ (row & 7);
      int cb1_ = (4 + rgrp) ^ (row & 7);
      bf16x8 aK0 = *(const bf16x8*)&sKc[row * 64 + cb0_ * 8];
      bf16x8 aK1 = *(const bf16x8*)&sKc[row * 64 + cb1_ * 8];
      sT[0][nt] = __builtin_amdgcn_mfma_f32_16x16x32_bf16(aK0, bQ[0][0], FZ, 0, 0, 0);
      sT[1][nt] = __builtin_amdgcn_mfma_f32_16x16x32_bf16(aK0, bQ[1][0], FZ, 0, 0, 0);
      sT[0][nt] = __builtin_amdgcn_mfma_f32_16x16x32_bf16(aK1, bQ[0][1], sT[0][nt], 0, 0, 0);
      sT[1][nt] = __builtin_amdgcn_mfma_f32_16x16x32_bf16(aK1, bQ[1][1], sT[1][nt], 0, 0, 0);
    }
    __builtin_amdgcn_s_setprio(0);
  };

  auto smpv = [&](const u16* sVc) {
    #pragma unroll
    for (int qg = 0; qg < 2; ++qg) {
      #pragma unroll
      for (int nt = 0; nt < 4; ++nt)
        #pragma unroll
        for (int r = 0; r < 4; ++r)
          sT[qg][nt][r] = __builtin_amdgcn_exp2f(sT[qg][nt][r]);

      u32 pw[4][2];
      #pragma unroll
      for (int nt = 0; nt < 4; ++nt) {
        pw[nt][0] = cvt_pk_bf16(sT[qg][nt][0], sT[qg][nt][1]);
        pw[nt][1] = cvt_pk_bf16(sT[qg][nt][2], sT[qg][nt][3]);
      }
      bf16x8 bP[2];
      #pragma unroll
      for (int kk = 0; kk < 2; ++kk) {
        u32 a0 = pw[2 * kk][0], b0 = pw[2 * kk + 1][0];
        u32 a1 = pw[2 * kk][1], b1 = pw[2 * kk + 1][1];
        asm("v_permlane32_swap_b32 %0, %1" : "+v"(a0), "+v"(b0));
        asm("v_permlane16_swap_b32 %0, %1" : "+v"(a0), "+v"(b0));
        asm("v_permlane32_swap_b32 %0, %1" : "+v"(a1), "+v"(b1));
        asm("v_permlane16_swap_b32 %0, %1" : "+v"(a1), "+v"(b1));
        union { u32 u[4]; bf16x8 v; } fu;
        fu.u[0] = a0; fu.u[1] = a1; fu.u[2] = b0; fu.u[3] = b1;
        bP[kk] = fu.v;
      }

      __builtin_amdgcn_s_setprio(1);
      #pragma unroll
      for (int kk = 0; kk < 2; ++kk) {
        lden[qg] = __builtin_amdgcn_mfma_f32_16x16x32_bf16(vones, bP[kk], lden[qg], 0, 0, 0);
        #pragma unroll
        for (int dt = 0; dt < 4; ++dt) {
          int rowv = dt * 16 + rlo;
          int cbv  = (kk * 4 + rgrp) ^ (rowv & 7);
          bf16x8 aV = *(const bf16x8*)&sVc[rowv * 64 + cbv * 8];
          o[qg][dt] = __builtin_amdgcn_mfma_f32_16x16x32_bf16(aV, bP[kk], o[qg][dt], 0, 0, 0);
        }
      }
      __builtin_amdgcn_s_setprio(0);
    }
  };

  auto iter = [&](const u16* sKc, const u16* sVc, u16* sKn, u16* sVn) {
    stage(sKn, sVn);                                  // K(t+1) x2, V(t+1) x2
    qk(sKc);
    asm volatile("s_waitcnt vmcnt(4)" ::: "memory");  // V(t) landed
    __builtin_amdgcn_s_barrier();
    __builtin_amdgcn_sched_barrier(0);
    smpv(sVc);
    asm volatile("s_waitcnt vmcnt(2)" ::: "memory");  // K(t+1) landed
    __builtin_amdgcn_s_barrier();
    __builtin_amdgcn_sched_barrier(0);
  };

  for (int it = 0; it < 15; ++it) {
    iter(sK[0], sV[0], sK[1], sV[1]);
    iter(sK[1], sV[1], sK[0], sV[0]);
  }
  iter(sK[0], sV[0], sK[1], sV[1]);                   // t=30, stages tile 31

  qk(sK[1]);
  asm volatile("s_waitcnt vmcnt(0)" ::: "memory");
  __builtin_amdgcn_s_barrier();
  __builtin_amdgcn_sched_barrier(0);
  smpv(sV[1]);

  #pragma unroll
  for (int qg = 0; qg < 2; ++qg) {
    const float inv = 1.0f / lden[qg][0];
    const int tq = qt * 128 + w * 32 + qg * 16 + rlo;
    #pragma unroll
    for (int dt = 0; dt < 4; ++dt) {
      uint2 st;
      st.x = cvt_pk_bf16(o[qg][dt][0] * inv, o[qg][dt][1] * inv);
      st.y = cvt_pk_bf16(o[qg][dt][2] * inv, o[qg][dt][3] * inv);
      *(uint2*)&O[((size_t)(b * 2048 + tq)) * 1024 + h * 64 + dt * 16 + rgrp * 4] = st;
    }
  }
}

// ---------------- launch ----------------

extern "C" void kernel_launch(void* const* d_in, const int* in_sizes, int n_in,
                              void* d_out, int out_size, void* d_ws, size_t ws_size,
                              hipStream_t stream) {
  const float* x  = (const float*)d_in[0];
  const float* Wq = (const float*)d_in[1];
  const float* bq = (const float*)d_in[2];
  const float* Wk = (const float*)d_in[3];
  const float* bk = (const float*)d_in[4];
  const float* Wv = (const float*)d_in[5];
  const float* bv = (const float*)d_in[6];
  const float* Wo = (const float*)d_in[7];
  const float* bo = (const float*)d_in[8];

  char* ws = (char*)d_ws;
  u16* xb  = (u16*)(ws);                      // 16 MiB  [8192][1024]
  u16* Wqb = (u16*)(ws + 16777216);           //  2 MiB
  u16* Wkb = (u16*)(ws + 18874368);
  u16* Wvb = (u16*)(ws + 20971520);
  u16* Wob = (u16*)(ws + 23068672);
  u16* Qb  = (u16*)(ws + 25165824);           // 16 MiB  [8192][1024]
  u16* Kb  = (u16*)(ws + 41943040);           // 16 MiB  [8192][1024] (pre-scaled)
  u16* Vtb = (u16*)(ws + 58720256);           // 16 MiB  [BH][64][T]
  u16* Ab  = (u16*)(ws + 75497472);           // 16 MiB  [B][T][1024]

  cvt_all_kernel<<<5120, 256, 0, stream>>>(x, Wq, Wk, Wv, Wo, xb, Wqb, Wkb, Wvb, Wob);

  gemm_qkv_kernel<<<1536, 256, 0, stream>>>(xb, Wqb, Wkb, Wvb, bq, bk, bv, Qb, Kb, Vtb);

  attn_kernel<<<1024, 256, 0, stream>>>(Qb, Kb, Vtb, (bf16*)Ab);

  gemm_out_kernel<<<512, 256, 0, stream>>>(Ab, Wob, bo, (float*)d_out);
}

// Round 14
// 211.067 us; speedup vs baseline: 1.0446x; 1.0038x over previous
//
#include <hip/hip_runtime.h>

typedef unsigned short u16;
typedef unsigned int   u32;
typedef __bf16 bf16;
typedef __attribute__((ext_vector_type(8))) __bf16 bf16x8;
typedef __attribute__((ext_vector_type(4))) float  f32x4;

// ---------------- helpers ----------------

__device__ __forceinline__ u16 f2bf(float f) {
  u32 u = __float_as_uint(f);
  u32 r = (u + 0x7fffu + ((u >> 16) & 1u)) >> 16;   // RNE
  return (u16)r;
}

// global -> LDS direct, 16B per lane. LDS dest is wave-uniform base + lane*16.
__device__ __forceinline__ void gload_lds16(const void* g, void* l) {
  __builtin_amdgcn_global_load_lds((__attribute__((address_space(1))) u32*)g,
                                   (__attribute__((address_space(3))) u32*)l,
                                   16, 0, 0);
}

__device__ __forceinline__ u32 cvt_pk_bf16(float lo, float hi) {
  u32 r;
  asm("v_cvt_pk_bf16_f32 %0, %1, %2" : "=v"(r) : "v"(lo), "v"(hi));
  return r;
}

#define SCL_LOG2E 0.1803368801111204f  /* (1/sqrt(64)) * log2(e) */

// ---------------- fused f32 -> bf16 convert (x + all 4 weights, one launch) ---

__global__ __launch_bounds__(256) void cvt_all_kernel(const float* __restrict__ x,
                                                      const float* __restrict__ p0,
                                                      const float* __restrict__ p1,
                                                      const float* __restrict__ p2,
                                                      const float* __restrict__ p3,
                                                      u16* __restrict__ xo,
                                                      u16* o0, u16* o1, u16* o2, u16* o3) {
  const int bid = blockIdx.x;
  if (bid < 4096) {
    int i = bid * 256 + threadIdx.x;            // 1M threads, 2M float4s
    #pragma unroll
    for (int r = 0; r < 2; ++r, i += 1048576) {
      float4 v = ((const float4*)x)[i];
      uint2 o;
      o.x = (u32)f2bf(v.x) | ((u32)f2bf(v.y) << 16);
      o.y = (u32)f2bf(v.z) | ((u32)f2bf(v.w) << 16);
      ((uint2*)xo)[i] = o;
    }
  } else {
    const int wb = bid - 4096;
    const int which = wb >> 8;
    const float* in = which == 0 ? p0 : which == 1 ? p1 : which == 2 ? p2 : p3;
    u16* out = which == 0 ? o0 : which == 1 ? o1 : which == 2 ? o2 : o3;
    int i = (wb & 255) * 256 + threadIdx.x;
    #pragma unroll
    for (int r = 0; r < 4; ++r, i += 65536) {
      float4 v = ((const float4*)in)[i];
      uint2 o;
      o.x = (u32)f2bf(v.x) | ((u32)f2bf(v.y) << 16);
      o.y = (u32)f2bf(v.z) | ((u32)f2bf(v.w) << 16);
      ((uint2*)out)[i] = o;
    }
  }
}

// ---------------- GEMM core (2-slot dbuf + syncthreads — best measured) ------

#define GK 1024
#define GN 1024

__global__ __launch_bounds__(256) void gemm_qkv_kernel(const u16* __restrict__ A,
                                                       const u16* __restrict__ Wq,
                                                       const u16* __restrict__ Wk,
                                                       const u16* __restrict__ Wv,
                                                       const float* __restrict__ bq,
                                                       const float* __restrict__ bk,
                                                       const float* __restrict__ bv,
                                                       u16* __restrict__ Qo,
                                                       u16* __restrict__ Ko,
                                                       u16* __restrict__ Vo) {
  __shared__ u16 sA[2][128 * 32];
  __shared__ u16 sB[2][128 * 32];

  const int tid  = threadIdx.x;
  const int lane = tid & 63;
  const int w    = tid >> 6;
  const int wm   = w >> 1, wn = w & 1;
  const int lid  = (blockIdx.x & 7) * 192 + (blockIdx.x >> 3);
  const int which = lid >> 9;            // 0..2
  const int sub   = lid & 511;
  const u16*  W    = which == 0 ? Wq : which == 1 ? Wk : Wv;
  const float* bias = which == 0 ? bq : which == 1 ? bk : bv;
  const int tn   = sub & 7;
  const int tm   = sub >> 3;
  const int m0   = tm * 128, n0 = tn * 128;
  const int rgrp = lane >> 4, rlo = lane & 15;

  const int c0 = (w * 2 + 0) * 64 + lane;
  const int c1 = (w * 2 + 1) * 64 + lane;
  const int r0 = c0 >> 2, col0 = (((c0 & 3) ^ (r0 & 3)) * 8);
  const int r1 = c1 >> 2, col1 = (((c1 & 3) ^ (r1 & 3)) * 8);
  const u16* aS0 = A + (size_t)(m0 + r0) * GK + col0;
  const u16* aS1 = A + (size_t)(m0 + r1) * GK + col1;
  const u16* bS0 = W + (size_t)(n0 + r0) * GK + col0;
  const u16* bS1 = W + (size_t)(n0 + r1) * GK + col1;

  auto stage = [&](u16* dA, u16* dB, int kt) {
    int k0 = kt * 32;
    gload_lds16(aS0 + k0, dA + (w * 2 + 0) * 512);
    gload_lds16(aS1 + k0, dA + (w * 2 + 1) * 512);
    gload_lds16(bS0 + k0, dB + (w * 2 + 0) * 512);
    gload_lds16(bS1 + k0, dB + (w * 2 + 1) * 512);
  };

  f32x4 acc[4][4] = {};

  auto compute = [&](const u16* sAc, const u16* sBc) {
    bf16x8 a[4], b[4];
    #pragma unroll
    for (int i = 0; i < 4; ++i) {
      int row = wm * 64 + i * 16 + rlo;
      int cb  = rgrp ^ (row & 3);
      a[i] = *(const bf16x8*)&sAc[row * 32 + cb * 8];
    }
    #pragma unroll
    for (int j = 0; j < 4; ++j) {
      int row = wn * 64 + j * 16 + rlo;
      int cb  = rgrp ^ (row & 3);
      b[j] = *(const bf16x8*)&sBc[row * 32 + cb * 8];
    }
    #pragma unroll
    for (int i = 0; i < 4; ++i)
      #pragma unroll
      for (int j = 0; j < 4; ++j)
        acc[i][j] = __builtin_amdgcn_mfma_f32_16x16x32_bf16(a[i], b[j], acc[i][j], 0, 0, 0);
  };

  stage(sA[0], sB[0], 0);
  __syncthreads();

  for (int kt = 0; kt < GK / 32; kt += 2) {
    stage(sA[1], sB[1], kt + 1);
    compute(sA[0], sB[0]);
    __syncthreads();
    if (kt + 2 < GK / 32) stage(sA[0], sB[0], kt + 2);
    compute(sA[1], sB[1]);
    __syncthreads();
  }

  if (which <= 1) {
    u16* out = which == 0 ? Qo : Ko;
    const float scl = which == 0 ? 1.0f : SCL_LOG2E;
    #pragma unroll
    for (int i = 0; i < 4; ++i)
      #pragma unroll
      for (int j = 0; j < 4; ++j)
        #pragma unroll
        for (int r = 0; r < 4; ++r) {
          int m = m0 + wm * 64 + i * 16 + rgrp * 4 + r;
          int n = n0 + wn * 64 + j * 16 + rlo;
          float v = (acc[i][j][r] + bias[n]) * scl;
          out[(size_t)m * GN + n] = (u16)__builtin_bit_cast(u16, (bf16)v);
        }
  } else {
    #pragma unroll
    for (int i = 0; i < 4; ++i)
      #pragma unroll
      for (int j = 0; j < 4; ++j) {
        int mb = m0 + wm * 64 + i * 16 + rgrp * 4;
        int n  = n0 + wn * 64 + j * 16 + rlo;
        int b = mb >> 11, t = mb & 2047, h = n >> 6, hd = n & 63;
        float bv_ = bias[n];
        uint2 st;
        st.x = cvt_pk_bf16(acc[i][j][0] + bv_, acc[i][j][1] + bv_);
        st.y = cvt_pk_bf16(acc[i][j][2] + bv_, acc[i][j][3] + bv_);
        *(uint2*)&Vo[((size_t)(b * 16 + h) * 64 + hd) * 2048 + t] = st;
      }
  }
}

__global__ __launch_bounds__(256) void gemm_out_kernel(const u16* __restrict__ A,
                                                       const u16* __restrict__ W,
                                                       const float* __restrict__ bias,
                                                       float* __restrict__ Cout) {
  __shared__ u16 sA[2][128 * 32];
  __shared__ u16 sB[2][128 * 32];

  const int tid  = threadIdx.x;
  const int lane = tid & 63;
  const int w    = tid >> 6;
  const int wm   = w >> 1, wn = w & 1;
  const int lid  = (blockIdx.x & 7) * 64 + (blockIdx.x >> 3);
  const int tn   = lid & 7;
  const int tm   = lid >> 3;
  const int m0   = tm * 128, n0 = tn * 128;
  const int rgrp = lane >> 4, rlo = lane & 15;

  const int c0 = (w * 2 + 0) * 64 + lane;
  const int c1 = (w * 2 + 1) * 64 + lane;
  const int r0 = c0 >> 2, col0 = (((c0 & 3) ^ (r0 & 3)) * 8);
  const int r1 = c1 >> 2, col1 = (((c1 & 3) ^ (r1 & 3)) * 8);
  const u16* aS0 = A + (size_t)(m0 + r0) * GK + col0;
  const u16* aS1 = A + (size_t)(m0 + r1) * GK + col1;
  const u16* bS0 = W + (size_t)(n0 + r0) * GK + col0;
  const u16* bS1 = W + (size_t)(n0 + r1) * GK + col1;

  auto stage = [&](u16* dA, u16* dB, int kt) {
    int k0 = kt * 32;
    gload_lds16(aS0 + k0, dA + (w * 2 + 0) * 512);
    gload_lds16(aS1 + k0, dA + (w * 2 + 1) * 512);
    gload_lds16(bS0 + k0, dB + (w * 2 + 0) * 512);
    gload_lds16(bS1 + k0, dB + (w * 2 + 1) * 512);
  };

  f32x4 acc[4][4] = {};

  auto compute = [&](const u16* sAc, const u16* sBc) {
    bf16x8 a[4], b[4];
    #pragma unroll
    for (int i = 0; i < 4; ++i) {
      int row = wm * 64 + i * 16 + rlo;
      int cb  = rgrp ^ (row & 3);
      a[i] = *(const bf16x8*)&sAc[row * 32 + cb * 8];
    }
    #pragma unroll
    for (int j = 0; j < 4; ++j) {
      int row = wn * 64 + j * 16 + rlo;
      int cb  = rgrp ^ (row & 3);
      b[j] = *(const bf16x8*)&sBc[row * 32 + cb * 8];
    }
    #pragma unroll
    for (int i = 0; i < 4; ++i)
      #pragma unroll
      for (int j = 0; j < 4; ++j)
        acc[i][j] = __builtin_amdgcn_mfma_f32_16x16x32_bf16(a[i], b[j], acc[i][j], 0, 0, 0);
  };

  stage(sA[0], sB[0], 0);
  __syncthreads();

  for (int kt = 0; kt < GK / 32; kt += 2) {
    stage(sA[1], sB[1], kt + 1);
    compute(sA[0], sB[0]);
    __syncthreads();
    if (kt + 2 < GK / 32) stage(sA[0], sB[0], kt + 2);
    compute(sA[1], sB[1]);
    __syncthreads();
  }

  #pragma unroll
  for (int i = 0; i < 4; ++i)
    #pragma unroll
    for (int j = 0; j < 4; ++j)
      #pragma unroll
      for (int r = 0; r < 4; ++r) {
        int m = m0 + wm * 64 + i * 16 + rgrp * 4 + r;
        int n = n0 + wn * 64 + j * 16 + rlo;
        Cout[(size_t)m * GN + n] = acc[i][j][r] + bias[n];
      }
}

// ---------------- fused flash attention (KVBLK=64, SINGLE-barrier pipeline) ---
// Q,K: [8192][1024] bf16; K PRE-SCALED by SCL_LOG2E. Vt: [BH][64][T] bf16.
// grid 1024 = bh*16 + qtile ; 4 waves x 32 q-rows (2 groups of 16), KV tile 64.
// Swapped QK^T; fixed-ref softmax (p = exp2(s)); in-register P->bf16 + permlane;
// PV as O^T = mfma(Vt, P); denominator via ones-MFMA; static dbuf.
//
// ONE barrier + ONE waitcnt per iteration (vs 2+2 before): both K(t+1) and
// V(t+1) get a FULL iteration (~3000 cyc) of flight, so the end-of-iter
// vmcnt(0) is a no-op wait in steady state and the mid-iteration publish
// point for V disappears entirely.
//   iter t: stage(t+1) -> QK^T(t) -> SM+PV(t) -> vmcnt(0) -> s_barrier.
// Ledger: iter t reads sK/sV[t&1], staged at t-1 and published by t-1's end
// vmcnt(0)+barrier; stage(t+1) writes buf[(t+1)&1], whose readers (iter t-1)
// all passed the end-of-(t-1) barrier; ds_reads retire via compiler lgkm
// before each wave reaches the barrier.

__global__ __launch_bounds__(256) void attn_kernel(const u16* __restrict__ Q,
                                                   const u16* __restrict__ K,
                                                   const u16* __restrict__ Vt,
                                                   bf16* __restrict__ O) {
  __shared__ u16 sK[2][64 * 64];
  __shared__ u16 sV[2][64 * 64];

  const int tid  = threadIdx.x;
  const int lane = tid & 63;
  const int w    = tid >> 6;
  const int rgrp = lane >> 4, rlo = lane & 15;
  const int bid  = (blockIdx.x & 7) * 128 + (blockIdx.x >> 3);
  const int qt   = bid & 15;
  const int bh   = bid >> 4;
  const int b    = bh >> 4, h = bh & 15;

  const u16* Qh = Q  + (size_t)b * 2048 * 1024 + h * 64;   // row stride 1024
  const u16* Kh = K  + (size_t)b * 2048 * 1024 + h * 64;   // row stride 1024
  const u16* Vh = Vt + (size_t)bh * 64 * 2048;             // row stride 2048

  const int c0 = (w * 2 + 0) * 64 + lane;
  const int c1 = (w * 2 + 1) * 64 + lane;
  const int r0 = c0 >> 3, col0 = ((c0 & 7) ^ (r0 & 7)) * 8;
  const int r1 = c1 >> 3, col1 = ((c1 & 7) ^ (r1 & 7)) * 8;
  const u16* kb0 = Kh + (size_t)r0 * 1024 + col0;
  const u16* kb1 = Kh + (size_t)r1 * 1024 + col1;
  const u16* vb0 = Vh + (size_t)r0 * 2048 + col0;
  const u16* vb1 = Vh + (size_t)r1 * 2048 + col1;

  auto stage = [&](u16* dK, u16* dV) {
    gload_lds16(kb0, dK + (w * 2 + 0) * 512);
    gload_lds16(kb1, dK + (w * 2 + 1) * 512);
    gload_lds16(vb0, dV + (w * 2 + 0) * 512);
    gload_lds16(vb1, dV + (w * 2 + 1) * 512);
    kb0 += 65536; kb1 += 65536;   // 64 kv rows * 1024
    vb0 += 64;    vb1 += 64;      // 64 kv cols
  };

  stage(sK[0], sV[0]);

  bf16x8 bQ[2][2];
  #pragma unroll
  for (int qg = 0; qg < 2; ++qg) {
    int q0 = qt * 128 + w * 32 + qg * 16 + rlo;
    bQ[qg][0] = *(const bf16x8*)&Qh[(size_t)q0 * 1024 + rgrp * 8];
    bQ[qg][1] = *(const bf16x8*)&Qh[(size_t)q0 * 1024 + 32 + rgrp * 8];
  }

  bf16x8 vones;
  #pragma unroll
  for (int i = 0; i < 8; ++i) vones[i] = (bf16)1.0f;
  const f32x4 FZ = {0.f, 0.f, 0.f, 0.f};

  asm volatile("s_waitcnt vmcnt(0)" ::: "memory");
  __builtin_amdgcn_s_barrier();
  __builtin_amdgcn_sched_barrier(0);

  f32x4 lden[2] = {};
  f32x4 o[2][4] = {};
  f32x4 sT[2][4];

  auto qk = [&](const u16* sKc) {
    __builtin_amdgcn_s_setprio(1);
    #pragma unroll
    for (int nt = 0; nt < 4; ++nt) {
      int row = nt * 16 + rlo;
      int cb0_ = (0 + rgrp) ^ (row & 7);
      int cb1_ = (4 + rgrp) ^ (row & 7);
      bf16x8 aK0 = *(const bf16x8*)&sKc[row * 64 + cb0_ * 8];
      bf16x8 aK1 = *(const bf16x8*)&sKc[row * 64 + cb1_ * 8];
      sT[0][nt] = __builtin_amdgcn_mfma_f32_16x16x32_bf16(aK0, bQ[0][0], FZ, 0, 0, 0);
      sT[1][nt] = __builtin_amdgcn_mfma_f32_16x16x32_bf16(aK0, bQ[1][0], FZ, 0, 0, 0);
      sT[0][nt] = __builtin_amdgcn_mfma_f32_16x16x32_bf16(aK1, bQ[0][1], sT[0][nt], 0, 0, 0);
      sT[1][nt] = __builtin_amdgcn_mfma_f32_16x16x32_bf16(aK1, bQ[1][1], sT[1][nt], 0, 0, 0);
    }
    __builtin_amdgcn_s_setprio(0);
  };

  auto smpv = [&](const u16* sVc) {
    #pragma unroll
    for (int qg = 0; qg < 2; ++qg) {
      #pragma unroll
      for (int nt = 0; nt < 4; ++nt)
        #pragma unroll
        for (int r = 0; r < 4; ++r)
          sT[qg][nt][r] = __builtin_amdgcn_exp2f(sT[qg][nt][r]);

      u32 pw[4][2];
      #pragma unroll
      for (int nt = 0; nt < 4; ++nt) {
        pw[nt][0] = cvt_pk_bf16(sT[qg][nt][0], sT[qg][nt][1]);
        pw[nt][1] = cvt_pk_bf16(sT[qg][nt][2], sT[qg][nt][3]);
      }
      bf16x8 bP[2];
      #pragma unroll
      for (int kk = 0; kk < 2; ++kk) {
        u32 a0 = pw[2 * kk][0], b0 = pw[2 * kk + 1][0];
        u32 a1 = pw[2 * kk][1], b1 = pw[2 * kk + 1][1];
        asm("v_permlane32_swap_b32 %0, %1" : "+v"(a0), "+v"(b0));
        asm("v_permlane16_swap_b32 %0, %1" : "+v"(a0), "+v"(b0));
        asm("v_permlane32_swap_b32 %0, %1" : "+v"(a1), "+v"(b1));
        asm("v_permlane16_swap_b32 %0, %1" : "+v"(a1), "+v"(b1));
        union { u32 u[4]; bf16x8 v; } fu;
        fu.u[0] = a0; fu.u[1] = a1; fu.u[2] = b0; fu.u[3] = b1;
        bP[kk] = fu.v;
      }

      __builtin_amdgcn_s_setprio(1);
      #pragma unroll
      for (int kk = 0; kk < 2; ++kk) {
        lden[qg] = __builtin_amdgcn_mfma_f32_16x16x32_bf16(vones, bP[kk], lden[qg], 0, 0, 0);
        #pragma unroll
        for (int dt = 0; dt < 4; ++dt) {
          int rowv = dt * 16 + rlo;
          int cbv  = (kk * 4 + rgrp) ^ (rowv & 7);
          bf16x8 aV = *(const bf16x8*)&sVc[rowv * 64 + cbv * 8];
          o[qg][dt] = __builtin_amdgcn_mfma_f32_16x16x32_bf16(aV, bP[kk], o[qg][dt], 0, 0, 0);
        }
      }
      __builtin_amdgcn_s_setprio(0);
    }
  };

  // single-barrier iteration: stage(t+1); qk(t); smpv(t); vmcnt(0); barrier
  auto iter = [&](const u16* sKc, const u16* sVc, u16* sKn, u16* sVn) {
    stage(sKn, sVn);
    qk(sKc);
    smpv(sVc);
    asm volatile("s_waitcnt vmcnt(0)" ::: "memory");
    __builtin_amdgcn_s_barrier();
    __builtin_amdgcn_sched_barrier(0);
  };

  for (int it = 0; it < 15; ++it) {
    iter(sK[0], sV[0], sK[1], sV[1]);
    iter(sK[1], sV[1], sK[0], sV[0]);
  }
  iter(sK[0], sV[0], sK[1], sV[1]);                   // t=30, stages tile 31

  // t = 31 (final): no stages, buffers already published by t=30's barrier
  qk(sK[1]);
  smpv(sV[1]);

  #pragma unroll
  for (int qg = 0; qg < 2; ++qg) {
    const float inv = 1.0f / lden[qg][0];
    const int tq = qt * 128 + w * 32 + qg * 16 + rlo;
    #pragma unroll
    for (int dt = 0; dt < 4; ++dt) {
      uint2 st;
      st.x = cvt_pk_bf16(o[qg][dt][0] * inv, o[qg][dt][1] * inv);
      st.y = cvt_pk_bf16(o[qg][dt][2] * inv, o[qg][dt][3] * inv);
      *(uint2*)&O[((size_t)(b * 2048 + tq)) * 1024 + h * 64 + dt * 16 + rgrp * 4] = st;
    }
  }
}

// ---------------- launch ----------------

extern "C" void kernel_launch(void* const* d_in, const int* in_sizes, int n_in,
                              void* d_out, int out_size, void* d_ws, size_t ws_size,
                              hipStream_t stream) {
  const float* x  = (const float*)d_in[0];
  const float* Wq = (const float*)d_in[1];
  const float* bq = (const float*)d_in[2];
  const float* Wk = (const float*)d_in[3];
  const float* bk = (const float*)d_in[4];
  const float* Wv = (const float*)d_in[5];
  const float* bv = (const float*)d_in[6];
  const float* Wo = (const float*)d_in[7];
  const float* bo = (const float*)d_in[8];

  char* ws = (char*)d_ws;
  u16* xb  = (u16*)(ws);                      // 16 MiB  [8192][1024]
  u16* Wqb = (u16*)(ws + 16777216);           //  2 MiB
  u16* Wkb = (u16*)(ws + 18874368);
  u16* Wvb = (u16*)(ws + 20971520);
  u16* Wob = (u16*)(ws + 23068672);
  u16* Qb  = (u16*)(ws + 25165824);           // 16 MiB  [8192][1024]
  u16* Kb  = (u16*)(ws + 41943040);           // 16 MiB  [8192][1024] (pre-scaled)
  u16* Vtb = (u16*)(ws + 58720256);           // 16 MiB  [BH][64][T]
  u16* Ab  = (u16*)(ws + 75497472);           // 16 MiB  [B][T][1024]

  cvt_all_kernel<<<5120, 256, 0, stream>>>(x, Wq, Wk, Wv, Wo, xb, Wqb, Wkb, Wvb, Wob);

  gemm_qkv_kernel<<<1536, 256, 0, stream>>>(xb, Wqb, Wkb, Wvb, bq, bk, bv, Qb, Kb, Vtb);

  attn_kernel<<<1024, 256, 0, stream>>>(Qb, Kb, Vtb, (bf16*)Ab);

  gemm_out_kernel<<<512, 256, 0, stream>>>(Ab, Wob, bo, (float*)d_out);
}